// Round 1
// baseline (116.823 us; speedup 1.0000x reference)
//
#include <hip/hip_runtime.h>

// ---------------- problem constants ----------------
#define B_N  32
#define CI   128
#define CO   256
#define HH   64
#define WW   64
#define HP   66          // padded height
#define WP   66          // padded width
#define KTOT 1152        // 9 taps * 128 ci
#define PIX  4096        // 64*64

#define XT_ELEMS ((size_t)B_N * HP * WP * CI)   // 17,842,176 bf16
#define XT_BYTES (XT_ELEMS * 2)                 // 35,684,352 B
#define WT_ELEMS ((size_t)CO * KTOT)
#define WT_BYTES (WT_ELEMS * 2)                 // 589,824 B
#define WS_NEEDED (XT_BYTES + WT_BYTES)

#define AS1 __attribute__((address_space(1)))
#define AS3 __attribute__((address_space(3)))

typedef __attribute__((ext_vector_type(8))) short bf16x8;          // MFMA A/B frag (8 bf16)
typedef __attribute__((ext_vector_type(4))) float f32x4;           // MFMA C/D frag
typedef __attribute__((ext_vector_type(8))) unsigned short us8;    // 16B bf16 vector

__device__ __forceinline__ unsigned short f2bf(float f) {
    unsigned int u = __builtin_bit_cast(unsigned int, f);
    u += 0x7fffu + ((u >> 16) & 1u);   // round-to-nearest-even
    return (unsigned short)(u >> 16);
}

__device__ __forceinline__ void gload_lds16(const void* g, void* l) {
    // async global->LDS, 16B per lane; LDS dest is wave-uniform base + lane*16
    __builtin_amdgcn_global_load_lds((const AS1 unsigned int*)g,
                                     (AS3 unsigned int*)l, 16, 0, 0);
}

// ---------------- prologue 1: NCHW fp32 -> padded NHWC bf16 ----------------
// grid = B_N*HH blocks (one per (b,h)), 256 threads (4 waves), lane = w.
__global__ void k_transpose(const float* __restrict__ X, unsigned short* __restrict__ Xt) {
    int bh   = blockIdx.x;
    int b    = bh >> 6, h = bh & 63;
    int wv   = threadIdx.x >> 6;     // wave 0..3 -> ci block of 32
    int lane = threadIdx.x & 63;     // w
    const float* src = X + (((size_t)(b * CI + wv * 32) * HH + h) << 6) + lane;
    us8 v[4];
#pragma unroll
    for (int j = 0; j < 32; ++j)
        v[j >> 3][j & 7] = f2bf(src[(size_t)j << 12]);   // stride = 64*64 per ci
    unsigned short* dst = Xt + ((size_t)(b * HP + h + 1) * WP + (lane + 1)) * CI + wv * 32;
#pragma unroll
    for (int q = 0; q < 4; ++q)
        *(us8*)(dst + q * 8) = v[q];                     // 64B contiguous per lane
}

// ---------------- prologue 2: weights -> Wt[co][k], k = tap*128 + ci ----------------
__global__ void k_prepw(const float* __restrict__ W, unsigned short* __restrict__ Wt) {
    int co = blockIdx.x;
    for (int k = threadIdx.x; k < KTOT; k += 256) {
        int tap = k >> 7, ci = k & 127;
        Wt[(size_t)co * KTOT + k] = f2bf(W[((size_t)co * CI + ci) * 9 + tap]);
    }
}

// ---------------- main: implicit-GEMM conv, 128x128 tile, BK=64, 4 waves ----------------
__global__ __launch_bounds__(256, 2) void k_conv_gemm(
    const unsigned short* __restrict__ Xt, const unsigned short* __restrict__ Wt,
    const float* __restrict__ bias, float* __restrict__ out) {

    __shared__ __attribute__((aligned(16))) unsigned short As[128 * 64];  // [co_local][k] 16KB
    __shared__ __attribute__((aligned(16))) unsigned short Bs[128 * 64];  // [p_local][k]  16KB

    const int bid = blockIdx.x;
    const int b   = bid >> 6;            // batch
    const int mb  = (bid >> 5) & 1;      // co block (2 of 128)
    const int nb  = bid & 31;            // p block (32 of 128)
    const int co0 = mb << 7;
    const int h0  = nb << 1;             // first output row of this p-block

    const int tid  = threadIdx.x;
    const int wv   = tid >> 6;
    const int lane = tid & 63;
    const int lr   = lane & 15;          // frag row/col
    const int lg   = lane >> 4;          // frag k-group
    const int wm   = wv >> 1, wn = wv & 1;

    const int srow = lane >> 3;               // staging: row within 8-row slab
    const int sg   = (lane & 7) ^ srow;       // inverse-swizzled source 16B-group

    f32x4 acc[4][4] = {};

    for (int s = 0; s < 18; ++s) {
        const int tap = s >> 1;
        const int ci0 = (s & 1) << 6;
        const int kh  = tap / 3;
        const int kw  = tap - kh * 3;
#pragma unroll
        for (int ii = 0; ii < 4; ++ii) {
            const int i = (wv << 2) + ii;                     // slab 0..15 (8 rows each)
            // A: Wt[co][s*64 + g*8], swizzle-compensated source group
            const int arow = co0 + (i << 3) + srow;
            gload_lds16(Wt + (size_t)arow * KTOT + (s << 6) + (sg << 3), &As[i << 9]);
            // B: implicit im2col from padded NHWC (pad offset cancels the -1)
            const int pl = (i << 3) + srow;                   // p_local 0..127
            const int hh = h0 + (pl >> 6) + kh;               // padded row, <= 65
            const int wc = (pl & 63) + kw;                    // padded col, <= 65
            gload_lds16(Xt + ((size_t)(b * HP + hh) * WP + wc) * CI + ci0 + (sg << 3),
                        &Bs[i << 9]);
        }
        __syncthreads();
#pragma unroll
        for (int kk = 0; kk < 2; ++kk) {
            bf16x8 af[4], bfr[4];
#pragma unroll
            for (int m = 0; m < 4; ++m) {
                const int row = (wm << 6) + (m << 4) + lr;
                const int g   = ((kk << 2) + lg) ^ (row & 7);   // swizzled read
                af[m] = *(const bf16x8*)&As[(row << 6) + (g << 3)];
            }
#pragma unroll
            for (int n = 0; n < 4; ++n) {
                const int row = (wn << 6) + (n << 4) + lr;
                const int g   = ((kk << 2) + lg) ^ (row & 7);
                bfr[n] = *(const bf16x8*)&Bs[(row << 6) + (g << 3)];
            }
#pragma unroll
            for (int m = 0; m < 4; ++m)
#pragma unroll
                for (int n = 0; n < 4; ++n)
                    acc[m][n] = __builtin_amdgcn_mfma_f32_16x16x32_bf16(
                        af[m], bfr[n], acc[m][n], 0, 0, 0);
        }
        __syncthreads();
    }

    // epilogue: C/D frag col = lane&15, row = (lane>>4)*4 + j  (m89-verified)
    const int p0 = nb << 7;
#pragma unroll
    for (int m = 0; m < 4; ++m) {
#pragma unroll
        for (int j = 0; j < 4; ++j) {
            const int co = co0 + (wm << 6) + (m << 4) + (lg << 2) + j;
            const float bv = bias[co];
            float* op = out + ((size_t)(b * CO + co) << 12) + p0 + (wn << 6) + lr;
#pragma unroll
            for (int n = 0; n < 4; ++n)
                op[n << 4] = acc[m][n][j] + bv;
        }
    }
}

// ---------------- fallback (only if ws too small): direct fp32 conv ----------------
__global__ void k_naive(const float* __restrict__ X, const float* __restrict__ W,
                        const float* __restrict__ bias, float* __restrict__ out) {
    long idx = (long)blockIdx.x * blockDim.x + threadIdx.x;
    if (idx >= (long)B_N * CO * PIX) return;
    int p = idx & 4095, co = (int)((idx >> 12) & 255), b = (int)(idx >> 20);
    int h = p >> 6, w = p & 63;
    float s = bias[co];
    for (int ci = 0; ci < CI; ++ci) {
        const float* xp = X + ((size_t)(b * CI + ci) << 12);
        const float* wp = W + ((size_t)(co * CI + ci)) * 9;
        for (int kh = 0; kh < 3; ++kh) {
            int hh2 = h + kh - 1; if ((unsigned)hh2 >= 64u) continue;
            for (int kw = 0; kw < 3; ++kw) {
                int ww2 = w + kw - 1; if ((unsigned)ww2 >= 64u) continue;
                s += xp[(hh2 << 6) + ww2] * wp[kh * 3 + kw];
            }
        }
    }
    out[idx] = s;
}

extern "C" void kernel_launch(void* const* d_in, const int* in_sizes, int n_in,
                              void* d_out, int out_size, void* d_ws, size_t ws_size,
                              hipStream_t stream) {
    const float* X    = (const float*)d_in[0];
    const float* W    = (const float*)d_in[1];
    const float* bias = (const float*)d_in[2];
    float* out = (float*)d_out;

    if (ws_size < WS_NEEDED) {
        long total = (long)B_N * CO * PIX;
        k_naive<<<(int)((total + 255) / 256), 256, 0, stream>>>(X, W, bias, out);
        return;
    }

    unsigned short* Xt = (unsigned short*)d_ws;
    unsigned short* Wt = (unsigned short*)((char*)d_ws + XT_BYTES);

    hipMemsetAsync(d_ws, 0, XT_BYTES, stream);                 // zero padding borders
    k_transpose<<<B_N * HH, 256, 0, stream>>>(X, Xt);          // 2048 blocks
    k_prepw<<<CO, 256, 0, stream>>>(W, Wt);                    // 256 blocks
    k_conv_gemm<<<B_N * 64, 256, 0, stream>>>(Xt, Wt, bias, out); // 2048 blocks
}